// Round 1
// baseline (39.802 us; speedup 1.0000x reference)
//
#include <hip/hip_runtime.h>
#include <hip/hip_bf16.h>
#include <cstddef>

#define N_NODES 100000
#define HIDDEN  128
#define N_EDGES 1600000

// Kernel 1: per-node partial dots  s_row[n] = dot(x[n], w[0:128]),
//                                  s_col[n] = dot(x[n], w[128:256])
// One 64-lane wave per node; lane l owns elements 2l, 2l+1.
__global__ void node_dots_kernel(const float* __restrict__ x,
                                 const float* __restrict__ w,
                                 float* __restrict__ s_row,
                                 float* __restrict__ s_col) {
    const int lane   = threadIdx.x & 63;
    const int wave   = (blockIdx.x * blockDim.x + threadIdx.x) >> 6;
    const int nwaves = (gridDim.x * blockDim.x) >> 6;

    // w fragments held in registers across the grid-stride loop
    const float wr0 = w[2 * lane];
    const float wr1 = w[2 * lane + 1];
    const float wc0 = w[HIDDEN + 2 * lane];
    const float wc1 = w[HIDDEN + 2 * lane + 1];

    for (int n = wave; n < N_NODES; n += nwaves) {
        const float2 v = *reinterpret_cast<const float2*>(
            x + (size_t)n * HIDDEN + 2 * lane);
        float pr = v.x * wr0 + v.y * wr1;
        float pc = v.x * wc0 + v.y * wc1;
        // 64-lane butterfly reduction
        #pragma unroll
        for (int off = 32; off > 0; off >>= 1) {
            pr += __shfl_down(pr, off, 64);
            pc += __shfl_down(pc, off, 64);
        }
        if (lane == 0) {
            s_row[n] = pr;
            s_col[n] = pc;
        }
    }
}

// Kernel 2: out[e] = sigmoid(s_row[row[e]] + s_col[col[e]])
// 4 edges per thread (int4 index load, float4 store).
__global__ void edge_sigmoid_kernel(const int* __restrict__ ei,
                                    const float* __restrict__ s_row,
                                    const float* __restrict__ s_col,
                                    float* __restrict__ out) {
    const int nquads = N_EDGES / 4;
    for (int q = blockIdx.x * blockDim.x + threadIdx.x; q < nquads;
         q += gridDim.x * blockDim.x) {
        const int4 r = *reinterpret_cast<const int4*>(ei + 4 * q);
        const int4 c = *reinterpret_cast<const int4*>(ei + N_EDGES + 4 * q);
        float4 z;
        z.x = s_row[r.x] + s_col[c.x];
        z.y = s_row[r.y] + s_col[c.y];
        z.z = s_row[r.z] + s_col[c.z];
        z.w = s_row[r.w] + s_col[c.w];
        float4 o;
        o.x = 1.0f / (1.0f + __expf(-z.x));
        o.y = 1.0f / (1.0f + __expf(-z.y));
        o.z = 1.0f / (1.0f + __expf(-z.z));
        o.w = 1.0f / (1.0f + __expf(-z.w));
        *reinterpret_cast<float4*>(out + 4 * q) = o;
    }
}

extern "C" void kernel_launch(void* const* d_in, const int* in_sizes, int n_in,
                              void* d_out, int out_size, void* d_ws, size_t ws_size,
                              hipStream_t stream) {
    const int*   edge_index = (const int*)d_in[0];   // (2, N_EDGES)
    const float* x          = (const float*)d_in[1]; // (N_NODES, HIDDEN)
    const float* att_weight = (const float*)d_in[2]; // (1, 2*HIDDEN)
    float*       out        = (float*)d_out;         // (N_EDGES, 1)

    float* s_row = (float*)d_ws;           // N_NODES floats
    float* s_col = s_row + N_NODES;        // N_NODES floats

    // Kernel 1: 2048 blocks x 256 threads = 8192 waves, grid-stride over nodes
    node_dots_kernel<<<2048, 256, 0, stream>>>(x, att_weight, s_row, s_col);

    // Kernel 2: grid-stride over 400000 quads
    edge_sigmoid_kernel<<<2048, 256, 0, stream>>>(edge_index, s_row, s_col, out);
}

// Round 3
// 32.827 us; speedup vs baseline: 1.2125x; 1.2125x over previous
//
#include <hip/hip_runtime.h>
#include <hip/hip_bf16.h>
#include <cstddef>

#define N_NODES 100000
#define HIDDEN  128
#define N_EDGES 1600000

typedef int   i32x4 __attribute__((ext_vector_type(4)));
typedef float f32x4 __attribute__((ext_vector_type(4)));

// Kernel 1: per-node dots. One wave handles 4 consecutive rows.
// lane l: row = quad*4 + (l>>4); owns elements 8*(l&15) .. 8*(l&15)+7.
// Wave load = 4 rows x 512B = 2048B contiguous, fully coalesced.
// Reduction: in-register sum of 8, then 4 shuffle steps within 16-lane groups.
__global__ __launch_bounds__(256) void node_dots_kernel(
        const float* __restrict__ x,
        const float* __restrict__ w,
        float* __restrict__ s_row,
        float* __restrict__ s_col) {
    const int tid  = blockIdx.x * blockDim.x + threadIdx.x;
    const int wid  = tid >> 6;          // wave id == row-quad id
    if (wid >= N_NODES / 4) return;
    const int lane = threadIdx.x & 63;
    const int sub  = lane & 15;         // position within row (16 lanes/row)
    const int rsub = lane >> 4;         // which of the 4 rows

    // w fragments (L2-hot after first touch)
    const f32x4 wr0 = *reinterpret_cast<const f32x4*>(w + 8 * sub);
    const f32x4 wr1 = *reinterpret_cast<const f32x4*>(w + 8 * sub + 4);
    const f32x4 wc0 = *reinterpret_cast<const f32x4*>(w + HIDDEN + 8 * sub);
    const f32x4 wc1 = *reinterpret_cast<const f32x4*>(w + HIDDEN + 8 * sub + 4);

    const int n = wid * 4 + rsub;
    const float* xp = x + (size_t)n * HIDDEN + 8 * sub;
    const f32x4 v0 = *reinterpret_cast<const f32x4*>(xp);
    const f32x4 v1 = *reinterpret_cast<const f32x4*>(xp + 4);

    float pr = v0.x * wr0.x + v0.y * wr0.y + v0.z * wr0.z + v0.w * wr0.w
             + v1.x * wr1.x + v1.y * wr1.y + v1.z * wr1.z + v1.w * wr1.w;
    float pc = v0.x * wc0.x + v0.y * wc0.y + v0.z * wc0.z + v0.w * wc0.w
             + v1.x * wc1.x + v1.y * wc1.y + v1.z * wc1.z + v1.w * wc1.w;

    // 16-lane group reduction; one shfl instruction reduces all 4 rows at once
    #pragma unroll
    for (int off = 8; off > 0; off >>= 1) {
        pr += __shfl_down(pr, off, 64);
        pc += __shfl_down(pc, off, 64);
    }
    if (sub == 0) {
        s_row[n] = pr;
        s_col[n] = pc;
    }
}

// Kernel 2: out[e] = sigmoid(s_row[row[e]] + s_col[col[e]])
// 8 edges per thread: 2x int4 index loads per side, 16 independent gathers.
__global__ __launch_bounds__(256) void edge_sigmoid_kernel(
        const int* __restrict__ ei,
        const float* __restrict__ s_row,
        const float* __restrict__ s_col,
        float* __restrict__ out) {
    const int t = blockIdx.x * blockDim.x + threadIdx.x;
    if (t >= N_EDGES / 8) return;

    const i32x4 r0 = __builtin_nontemporal_load(
        reinterpret_cast<const i32x4*>(ei + 8 * t));
    const i32x4 r1 = __builtin_nontemporal_load(
        reinterpret_cast<const i32x4*>(ei + 8 * t + 4));
    const i32x4 c0 = __builtin_nontemporal_load(
        reinterpret_cast<const i32x4*>(ei + N_EDGES + 8 * t));
    const i32x4 c1 = __builtin_nontemporal_load(
        reinterpret_cast<const i32x4*>(ei + N_EDGES + 8 * t + 4));

    float z[8];
    z[0] = s_row[r0.x] + s_col[c0.x];
    z[1] = s_row[r0.y] + s_col[c0.y];
    z[2] = s_row[r0.z] + s_col[c0.z];
    z[3] = s_row[r0.w] + s_col[c0.w];
    z[4] = s_row[r1.x] + s_col[c1.x];
    z[5] = s_row[r1.y] + s_col[c1.y];
    z[6] = s_row[r1.z] + s_col[c1.z];
    z[7] = s_row[r1.w] + s_col[c1.w];

    f32x4 o0, o1;
    o0.x = 1.0f / (1.0f + __expf(-z[0]));
    o0.y = 1.0f / (1.0f + __expf(-z[1]));
    o0.z = 1.0f / (1.0f + __expf(-z[2]));
    o0.w = 1.0f / (1.0f + __expf(-z[3]));
    o1.x = 1.0f / (1.0f + __expf(-z[4]));
    o1.y = 1.0f / (1.0f + __expf(-z[5]));
    o1.z = 1.0f / (1.0f + __expf(-z[6]));
    o1.w = 1.0f / (1.0f + __expf(-z[7]));
    __builtin_nontemporal_store(o0, reinterpret_cast<f32x4*>(out + 8 * t));
    __builtin_nontemporal_store(o1, reinterpret_cast<f32x4*>(out + 8 * t + 4));
}

extern "C" void kernel_launch(void* const* d_in, const int* in_sizes, int n_in,
                              void* d_out, int out_size, void* d_ws, size_t ws_size,
                              hipStream_t stream) {
    const int*   edge_index = (const int*)d_in[0];   // (2, N_EDGES) int32
    const float* x          = (const float*)d_in[1]; // (N_NODES, HIDDEN)
    const float* att_weight = (const float*)d_in[2]; // (1, 2*HIDDEN)
    float*       out        = (float*)d_out;         // (N_EDGES, 1)

    float* s_row = (float*)d_ws;           // N_NODES floats
    float* s_col = s_row + N_NODES;        // N_NODES floats

    // 25000 waves exactly (N_NODES/4 quads), 4 waves/block -> 6250 blocks
    node_dots_kernel<<<6250, 256, 0, stream>>>(x, att_weight, s_row, s_col);

    // 200000 threads (8 edges each) -> 782 blocks
    edge_sigmoid_kernel<<<(N_EDGES / 8 + 255) / 256, 256, 0, stream>>>(
        edge_index, s_row, s_col, out);
}

// Round 4
// 32.336 us; speedup vs baseline: 1.2309x; 1.0152x over previous
//
#include <hip/hip_runtime.h>
#include <hip/hip_bf16.h>
#include <cstddef>

#define N_NODES 100000
#define HIDDEN  128
#define N_EDGES 1600000

typedef int   i32x4 __attribute__((ext_vector_type(4)));
typedef float f32x4 __attribute__((ext_vector_type(4)));

__device__ __forceinline__ float dot8(const f32x4 a0, const f32x4 a1,
                                      const f32x4 b0, const f32x4 b1) {
    return a0.x * b0.x + a0.y * b0.y + a0.z * b0.z + a0.w * b0.w
         + a1.x * b1.x + a1.y * b1.y + a1.z * b1.z + a1.w * b1.w;
}

// Kernel 1: per-node dots. One wave owns 4 consecutive quads = 16 rows = 8KB.
// lane l: sub = l&15 owns elements 8*sub..8*sub+7 of row 4*(q0+k) + (l>>4).
// All 8 load-pairs issued up-front -> 8KB independent bytes in flight/wave.
// Reduction: 4 shuffle steps within 16-lane groups reduce 4 rows at once.
__global__ __launch_bounds__(256) void node_dots_kernel(
        const float* __restrict__ x,
        const float* __restrict__ w,
        float* __restrict__ s_row,
        float* __restrict__ s_col) {
    const int tid = blockIdx.x * blockDim.x + threadIdx.x;
    const int wv  = tid >> 6;             // wave id in [0, 6250)
    if (wv >= N_NODES / 16) return;
    const int lane = threadIdx.x & 63;
    const int sub  = lane & 15;           // position within row (16 lanes/row)
    const int rsub = lane >> 4;           // which of the 4 rows in a quad

    // w fragments, loaded once per wave, reused for 16 rows (L2-hot)
    const f32x4 wr0 = *reinterpret_cast<const f32x4*>(w + 8 * sub);
    const f32x4 wr1 = *reinterpret_cast<const f32x4*>(w + 8 * sub + 4);
    const f32x4 wc0 = *reinterpret_cast<const f32x4*>(w + HIDDEN + 8 * sub);
    const f32x4 wc1 = *reinterpret_cast<const f32x4*>(w + HIDDEN + 8 * sub + 4);

    const int q0 = wv * 4;                // first quad (4 rows each)

    f32x4 v0[4], v1[4];
    #pragma unroll
    for (int k = 0; k < 4; ++k) {
        const float* xp = x + ((size_t)(q0 + k) * 4 + rsub) * HIDDEN + 8 * sub;
        v0[k] = *reinterpret_cast<const f32x4*>(xp);
        v1[k] = *reinterpret_cast<const f32x4*>(xp + 4);
    }

    #pragma unroll
    for (int k = 0; k < 4; ++k) {
        float pr = dot8(v0[k], v1[k], wr0, wr1);
        float pc = dot8(v0[k], v1[k], wc0, wc1);
        #pragma unroll
        for (int off = 8; off > 0; off >>= 1) {
            pr += __shfl_down(pr, off, 64);
            pc += __shfl_down(pc, off, 64);
        }
        if (sub == 0) {
            const int n = 4 * (q0 + k) + rsub;
            s_row[n] = pr;
            s_col[n] = pc;
        }
    }
}

// Kernel 2: out[e] = sigmoid(s_row[row[e]] + s_col[col[e]])
// 4 edges per thread -> 1563 blocks (~24 waves/CU) for gather-latency hiding.
__global__ __launch_bounds__(256) void edge_sigmoid_kernel(
        const int* __restrict__ ei,
        const float* __restrict__ s_row,
        const float* __restrict__ s_col,
        float* __restrict__ out) {
    const int t = blockIdx.x * blockDim.x + threadIdx.x;
    if (t >= N_EDGES / 4) return;

    const i32x4 r = __builtin_nontemporal_load(
        reinterpret_cast<const i32x4*>(ei + 4 * t));
    const i32x4 c = __builtin_nontemporal_load(
        reinterpret_cast<const i32x4*>(ei + N_EDGES + 4 * t));

    float z0 = s_row[r.x] + s_col[c.x];
    float z1 = s_row[r.y] + s_col[c.y];
    float z2 = s_row[r.z] + s_col[c.z];
    float z3 = s_row[r.w] + s_col[c.w];

    f32x4 o;
    o.x = 1.0f / (1.0f + __expf(-z0));
    o.y = 1.0f / (1.0f + __expf(-z1));
    o.z = 1.0f / (1.0f + __expf(-z2));
    o.w = 1.0f / (1.0f + __expf(-z3));
    __builtin_nontemporal_store(o, reinterpret_cast<f32x4*>(out + 4 * t));
}

extern "C" void kernel_launch(void* const* d_in, const int* in_sizes, int n_in,
                              void* d_out, int out_size, void* d_ws, size_t ws_size,
                              hipStream_t stream) {
    const int*   edge_index = (const int*)d_in[0];   // (2, N_EDGES) int32
    const float* x          = (const float*)d_in[1]; // (N_NODES, HIDDEN)
    const float* att_weight = (const float*)d_in[2]; // (1, 2*HIDDEN)
    float*       out        = (float*)d_out;         // (N_EDGES, 1)

    float* s_row = (float*)d_ws;           // N_NODES floats
    float* s_col = s_row + N_NODES;        // N_NODES floats

    // 6250 waves (4 quads each), 4 waves/block -> 1563 blocks
    node_dots_kernel<<<(N_NODES / 16 + 3) / 4, 256, 0, stream>>>(
        x, att_weight, s_row, s_col);

    // 400000 threads (4 edges each) -> 1563 blocks
    edge_sigmoid_kernel<<<(N_EDGES / 4 + 255) / 256, 256, 0, stream>>>(
        edge_index, s_row, s_col, out);
}